// Round 8
// baseline (236.076 us; speedup 1.0000x reference)
//
#include <hip/hip_runtime.h>
#include <hip/hip_bf16.h>

// Shapes: n_atoms=50000, hidden=32, num_irreps=16, out_ch=32, n_edges=800000
// Plain dispatches only (cooperative launch breaks this harness's graph capture).
// Pipeline:
//   zero_repack: counts=0 + W -> B-fragment bf16 (one dispatch)
//   histogram | scan_blocks | scan_sums | add_offsets | scatter(Y bf16 + src)
//   accumulate: one wave per target atom, 8-edge software pipeline,
//     agg[t][h*16+i] += nf[src,h]*Y[i]  (nf 6.4 MB, L2-resident), bf16 store
//   gemm: out = agg @ W + b via mfma_f32_16x16x32_bf16

#define HIDDEN 32
#define IRREPS 16
#define OUTCH  32

// ---------------- zero counts + repack W ------------------------------------
__global__ __launch_bounds__(256)
void zero_repack_kernel(const float* __restrict__ W,
                        int* __restrict__ counts,
                        __hip_bfloat16* __restrict__ w2frag, int n_atoms) {
    const int tid = blockIdx.x * blockDim.x + threadIdx.x;
    for (int i = tid; i < n_atoms; i += gridDim.x * blockDim.x) counts[i] = 0;
    if (tid < 2048) {
        const int lane = tid & 63;
        const int kk   = tid >> 7;
        const int n    = (((tid >> 6) & 1) << 4) + (lane & 15);
        const int kb   = kk * 32 + (lane >> 4) * 8;
#pragma unroll
        for (int j = 0; j < 8; ++j)
            w2frag[tid * 8 + j] = __float2bfloat16(W[(kb + j) * OUTCH + n]);
    }
}

// ---------------- CSR build -------------------------------------------------
__global__ void histogram_kernel(const int* __restrict__ ei,
                                 int* __restrict__ counts, int n_edges) {
    int e = blockIdx.x * blockDim.x + threadIdx.x;
    if (e < n_edges) atomicAdd(&counts[ei[n_edges + e]], 1);
}

__global__ __launch_bounds__(256)
void scan_blocks_kernel(const int* __restrict__ counts,
                        int* __restrict__ partial,
                        int* __restrict__ blocksums, int n) {
    __shared__ int s[256];
    const int tid = threadIdx.x;
    const int i = blockIdx.x * 256 + tid;
    const int v = (i < n) ? counts[i] : 0;
    s[tid] = v;
    __syncthreads();
    for (int off = 1; off < 256; off <<= 1) {
        int add = (tid >= off) ? s[tid - off] : 0;
        __syncthreads();
        if (tid >= off) s[tid] += add;
        __syncthreads();
    }
    if (i < n) partial[i] = s[tid] - v;          // exclusive within block
    if (tid == 255) blocksums[blockIdx.x] = s[255];
}

// nb <= 256: single-block parallel exclusive scan
__global__ __launch_bounds__(256)
void scan_sums_kernel(int* __restrict__ blocksums, int nb) {
    __shared__ int s[256];
    const int tid = threadIdx.x;
    const int v = (tid < nb) ? blocksums[tid] : 0;
    s[tid] = v;
    __syncthreads();
    for (int off = 1; off < 256; off <<= 1) {
        int add = (tid >= off) ? s[tid - off] : 0;
        __syncthreads();
        if (tid >= off) s[tid] += add;
        __syncthreads();
    }
    if (tid < nb) blocksums[tid] = s[tid] - v;   // exclusive
}

__global__ void add_offsets_kernel(const int* __restrict__ partial,
                                   const int* __restrict__ blocksums,
                                   const int* __restrict__ counts,
                                   int2* __restrict__ seg,
                                   int* __restrict__ cursor, int n) {
    int i = blockIdx.x * blockDim.x + threadIdx.x;
    if (i < n) {
        int off = partial[i] + blocksums[i >> 8];
        seg[i]    = make_int2(off, counts[i]);
        cursor[i] = off;
    }
}

// scatter edge -> CSR slot: srcs[pos] = src, Yb[pos][0..15] = SH basis (bf16)
__global__ void scatter_records_kernel(const float* __restrict__ ev,
                                       const int* __restrict__ ei,
                                       int* __restrict__ cursor,
                                       int* __restrict__ srcs,
                                       __hip_bfloat16* __restrict__ Yb,
                                       int n_edges) {
    int e = blockIdx.x * blockDim.x + threadIdx.x;
    if (e >= n_edges) return;
    const int src = ei[e];
    const int tgt = ei[n_edges + e];
    const float vx = ev[3 * e + 0];
    const float vy = ev[3 * e + 1];
    const float vz = ev[3 * e + 2];
    const float r    = sqrtf(vx * vx + vy * vy + vz * vz);
    const float rinv = 1.0f / fmaxf(r, 1e-12f);
    const float x = vx * rinv, y = vy * rinv, z = vz * rinv;
    const float x2 = x * x, y2 = y * y, z2 = z * z;

    float Y[IRREPS];
    Y[0]  = 0.28209479177387814f;
    Y[1]  = 0.4886025119029199f * y;
    Y[2]  = 0.4886025119029199f * z;
    Y[3]  = 0.4886025119029199f * x;
    Y[4]  = 1.0925484305920792f * x * y;
    Y[5]  = 1.0925484305920792f * y * z;
    Y[6]  = 0.31539156525252005f * (3.0f * z2 - 1.0f);
    Y[7]  = 1.0925484305920792f * x * z;
    Y[8]  = 0.5462742152960396f * (x2 - y2);
    Y[9]  = 0.5900435899266435f * y * (3.0f * x2 - y2);
    Y[10] = 2.890611442640554f * x * y * z;
    Y[11] = 0.4570457994644658f * y * (5.0f * z2 - 1.0f);
    Y[12] = 0.3731763325901154f * z * (5.0f * z2 - 3.0f);
    Y[13] = 0.4570457994644658f * x * (5.0f * z2 - 1.0f);
    Y[14] = 1.445305721320277f * z * (x2 - y2);
    Y[15] = 0.5900435899266435f * x * (x2 - 3.0f * y2);

    const int pos = atomicAdd(&cursor[tgt], 1);
    srcs[pos] = src;

    __hip_bfloat162 yp[8];
#pragma unroll
    for (int i = 0; i < 8; ++i) {
        yp[i].x = __float2bfloat16(Y[2 * i]);
        yp[i].y = __float2bfloat16(Y[2 * i + 1]);
    }
    uint4* dst = (uint4*)(Yb + (size_t)pos * IRREPS);
    dst[0] = ((const uint4*)yp)[0];
    dst[1] = ((const uint4*)yp)[1];
}

// ---------------- accumulate: one wave per target atom, 8-deep pipeline -----
__device__ __forceinline__ float2 bf2f2(unsigned u) {
    return __bfloat1622float2(*(const __hip_bfloat162*)&u);
}

__global__ __launch_bounds__(256)
void accumulate_agg_kernel(const int* __restrict__ srcs,
                           const __hip_bfloat16* __restrict__ Yb,
                           const int2* __restrict__ seg,
                           const float* __restrict__ nf,
                           __hip_bfloat16* __restrict__ aggb, int n_atoms) {
    const int w = (blockIdx.x * blockDim.x + threadIdx.x) >> 6;
    if (w >= n_atoms) return;
    const int lane = threadIdx.x & 63;
    const int h  = lane >> 1;
    const int ih = lane & 1;

    const int2 sg   = seg[w];
    const int start = __builtin_amdgcn_readfirstlane(sg.x);
    const int k     = __builtin_amdgcn_readfirstlane(sg.y);

    const int* sp = srcs + start;
    const __hip_bfloat16* yb = Yb + (size_t)start * IRREPS + ih * 8;

    float a0 = 0.f, a1 = 0.f, a2 = 0.f, a3 = 0.f;
    float a4 = 0.f, a5 = 0.f, a6 = 0.f, a7 = 0.f;

    for (int base = 0; base < k; base += 8) {
        float v[8];
        uint4 yq[8];
        // issue all 8 uniform src loads + nf gathers before any FMA use
#pragma unroll
        for (int i = 0; i < 8; ++i) {
            const int j  = base + i;
            const int jc = (j < k) ? j : (k - 1);           // uniform clamp
            const int s  = __builtin_amdgcn_readfirstlane(sp[jc]);
            v[i] = nf[s * HIDDEN + h];                      // L2-resident gather
        }
#pragma unroll
        for (int i = 0; i < 8; ++i) {
            const int j = base + i;
            if (j < k) yq[i] = *(const uint4*)(yb + (size_t)j * IRREPS);
            else       yq[i] = make_uint4(0u, 0u, 0u, 0u);  // zero-weight pad
        }
#pragma unroll
        for (int i = 0; i < 8; ++i) {
            const float2 p0 = bf2f2(yq[i].x);
            const float2 p1 = bf2f2(yq[i].y);
            const float2 p2 = bf2f2(yq[i].z);
            const float2 p3 = bf2f2(yq[i].w);
            a0 = fmaf(v[i], p0.x, a0); a1 = fmaf(v[i], p0.y, a1);
            a2 = fmaf(v[i], p1.x, a2); a3 = fmaf(v[i], p1.y, a3);
            a4 = fmaf(v[i], p2.x, a4); a5 = fmaf(v[i], p2.y, a5);
            a6 = fmaf(v[i], p3.x, a6); a7 = fmaf(v[i], p3.y, a7);
        }
    }

    __hip_bfloat162 o[4];
    o[0].x = __float2bfloat16(a0); o[0].y = __float2bfloat16(a1);
    o[1].x = __float2bfloat16(a2); o[1].y = __float2bfloat16(a3);
    o[2].x = __float2bfloat16(a4); o[2].y = __float2bfloat16(a5);
    o[3].x = __float2bfloat16(a6); o[3].y = __float2bfloat16(a7);
    *(uint4*)(aggb + (size_t)w * 512 + h * 16 + ih * 8) = *(const uint4*)o;
}

// ---------------- GEMM: out = agg @ W + b via MFMA --------------------------
typedef __attribute__((ext_vector_type(8))) short frag8;
typedef __attribute__((ext_vector_type(4))) float f32x4;

__global__ __launch_bounds__(256)
void gemm_kernel(const __hip_bfloat16* __restrict__ aggb,
                 const __hip_bfloat16* __restrict__ w2frag,
                 const float* __restrict__ b,
                 float* __restrict__ out, int n_atoms) {
    const int wave = (blockIdx.x * blockDim.x + threadIdx.x) >> 6;  // M-tile id
    const int tile0 = wave * 16;
    if (tile0 >= n_atoms) return;
    const int lane = threadIdx.x & 63;
    const int m    = lane & 15;
    const int quad = lane >> 4;

    const int mrow = min(tile0 + m, n_atoms - 1);
    const short* arow = (const short*)aggb + (size_t)mrow * 512 + quad * 8;
    const short* wf   = (const short*)w2frag;

    f32x4 acc0 = {0.f, 0.f, 0.f, 0.f};
    f32x4 acc1 = {0.f, 0.f, 0.f, 0.f};
#pragma unroll
    for (int kk = 0; kk < 16; ++kk) {
        frag8 a  = *(const frag8*)(arow + kk * 32);
        frag8 b0 = *(const frag8*)(wf + ((kk * 2 + 0) * 64 + lane) * 8);
        frag8 b1 = *(const frag8*)(wf + ((kk * 2 + 1) * 64 + lane) * 8);
        acc0 = __builtin_amdgcn_mfma_f32_16x16x32_bf16(a, b0, acc0, 0, 0, 0);
        acc1 = __builtin_amdgcn_mfma_f32_16x16x32_bf16(a, b1, acc1, 0, 0, 0);
    }

    // D: row = quad*4 + reg, col = lane&15
    const float bias0 = b[m];
    const float bias1 = b[16 + m];
    float* obase = out + (size_t)(tile0 + quad * 4) * OUTCH;
#pragma unroll
    for (int r = 0; r < 4; ++r) {
        if (tile0 + quad * 4 + r < n_atoms) {
            obase[r * OUTCH + m]      = acc0[r] + bias0;
            obase[r * OUTCH + 16 + m] = acc1[r] + bias1;
        }
    }
}

// ---------------- launch ---------------------------------------------------
extern "C" void kernel_launch(void* const* d_in, const int* in_sizes, int n_in,
                              void* d_out, int out_size, void* d_ws, size_t ws_size,
                              hipStream_t stream) {
    const float* nf = (const float*)d_in[0];
    const float* ev = (const float*)d_in[1];
    const int*   ei = (const int*)d_in[2];
    const float* W  = (const float*)d_in[3];
    const float* b  = (const float*)d_in[4];
    float* out = (float*)d_out;

    const int n_atoms = in_sizes[0] / HIDDEN;
    const int n_edges = in_sizes[1] / 3;
    const int nblk    = (n_atoms + 255) / 256;

    char* ws = (char*)d_ws;
    size_t off = 0;
    auto carve = [&](size_t bytes) { void* p = ws + off; off = (off + bytes + 255) & ~(size_t)255; return p; };
    __hip_bfloat16* aggb   = (__hip_bfloat16*)carve((size_t)n_atoms * 512 * 2);    // 51.2 MB
    __hip_bfloat16* Yb     = (__hip_bfloat16*)carve((size_t)n_edges * IRREPS * 2); // 25.6 MB
    int*            srcs   = (int*)carve((size_t)n_edges * 4 + 64);                // 3.2 MB
    __hip_bfloat16* w2frag = (__hip_bfloat16*)carve(2048 * 8 * 2);
    int*  counts    = (int*)carve((size_t)n_atoms * 4);
    int*  partial   = (int*)carve((size_t)n_atoms * 4);
    int2* seg       = (int2*)carve((size_t)n_atoms * 8);
    int*  cursor    = (int*)carve((size_t)n_atoms * 4);
    int*  blocksums = (int*)carve((size_t)nblk * 4);

    zero_repack_kernel<<<64, 256, 0, stream>>>(W, counts, w2frag, n_atoms);
    histogram_kernel<<<(n_edges + 255) / 256, 256, 0, stream>>>(ei, counts, n_edges);
    scan_blocks_kernel<<<nblk, 256, 0, stream>>>(counts, partial, blocksums, n_atoms);
    scan_sums_kernel<<<1, 256, 0, stream>>>(blocksums, nblk);
    add_offsets_kernel<<<nblk, 256, 0, stream>>>(partial, blocksums, counts, seg, cursor, n_atoms);
    scatter_records_kernel<<<(n_edges + 255) / 256, 256, 0, stream>>>(
        ev, ei, cursor, srcs, Yb, n_edges);

    const long long accthreads = (long long)n_atoms * 64;
    accumulate_agg_kernel<<<(int)((accthreads + 255) / 256), 256, 0, stream>>>(
        srcs, Yb, seg, nf, aggb, n_atoms);

    const int mtiles = (n_atoms + 15) / 16;
    gemm_kernel<<<(mtiles * 64 + 255) / 256, 256, 0, stream>>>(aggb, w2frag, b, out, n_atoms);
}